// Round 1
// baseline (143.459 us; speedup 1.0000x reference)
//
#include <hip/hip_runtime.h>

// Problem constants (from reference): B=4, DIM=512, CTX_DIM=768, H=W=48, NUM_HEADS=8
// Structural collapse: context is broadcast over all spatial positions, so all
// K rows (and V rows) are identical per batch -> softmax is exactly uniform ->
// attention output == V (independent of x and Wq). Full op reduces to
//   y[b,:] = (context[b] @ Wv) @ Wo + bo ;  out[b,c,h,w] = y[b,c].

#define BB   4
#define DIMC 512
#define CTXC 768
#define NPIX 2304            // 48*48
#define NVEC (BB * DIMC * (NPIX / 4))   // float4 count of the output

// Kernel 1: per-batch fused projection. One block per batch, 512 threads.
// Thread d computes v[d] = sum_c ctx[c]*Wv[c,d] (Wv stored [in,out] row-major,
// so Wv[c*DIMC+d] -> coalesced across threads), stages v in LDS, then
// y[d] = bo[d] + sum_c v[c]*Wo[c,d].
__global__ __launch_bounds__(DIMC) void ca_proj_kernel(
    const float* __restrict__ ctx,   // [BB, CTXC]
    const float* __restrict__ Wv,    // [CTXC, DIMC]
    const float* __restrict__ Wo,    // [DIMC, DIMC]
    const float* __restrict__ bo,    // [DIMC]
    float* __restrict__ y)           // [BB, DIMC] (workspace)
{
    __shared__ float v_s[DIMC];
    const int b = blockIdx.x;
    const int d = threadIdx.x;
    const float* cb = ctx + b * CTXC;

    float acc = 0.f;
#pragma unroll 8
    for (int c = 0; c < CTXC; ++c) {
        // cb[c] is wave-uniform -> scalar load; Wv column read is coalesced.
        acc += cb[c] * Wv[c * DIMC + d];
    }
    v_s[d] = acc;
    __syncthreads();

    float acc2 = bo[d];
#pragma unroll 8
    for (int c = 0; c < DIMC; ++c) {
        // v_s[c] is uniform across the wave -> LDS broadcast, no bank conflict.
        acc2 += v_s[c] * Wo[c * DIMC + d];
    }
    y[b * DIMC + d] = acc2;
}

// Kernel 2: broadcast y[b,c] across the 2304 spatial positions with float4
// stores. Each (b,c) row is 576 float4s; flat grid-stride with a cheap
// magic-number division recovers the row index.
__global__ __launch_bounds__(256) void ca_bcast_kernel(
    const float* __restrict__ y,     // [BB, DIMC]
    float4* __restrict__ out)        // [BB, DIMC, NPIX/4]
{
    const int per_row = NPIX / 4;    // 576
    const int stride = gridDim.x * blockDim.x;
    for (int i = blockIdx.x * blockDim.x + threadIdx.x; i < NVEC; i += stride) {
        const int row = i / per_row; // b*DIMC + c
        const float v = y[row];
        out[i] = make_float4(v, v, v, v);
    }
}

extern "C" void kernel_launch(void* const* d_in, const int* in_sizes, int n_in,
                              void* d_out, int out_size, void* d_ws, size_t ws_size,
                              hipStream_t stream) {
    // setup_inputs order: x, context, Wq, Wk, Wv, Wo, bo
    const float* ctx = (const float*)d_in[1];
    const float* Wv  = (const float*)d_in[4];
    const float* Wo  = (const float*)d_in[5];
    const float* bo  = (const float*)d_in[6];
    float* out = (float*)d_out;
    float* y   = (float*)d_ws;       // BB*DIMC floats = 8 KiB scratch

    ca_proj_kernel<<<BB, DIMC, 0, stream>>>(ctx, Wv, Wo, bo, y);

    // 18.87 MB of output; 2048 blocks x 256 threads -> ~2.25 float4/thread.
    ca_bcast_kernel<<<2048, 256, 0, stream>>>(y, (float4*)out);
}

// Round 2
// 88.462 us; speedup vs baseline: 1.6217x; 1.6217x over previous
//
#include <hip/hip_runtime.h>

// Structural collapse (verified passing in R1): context is broadcast over all
// spatial positions -> all K/V rows identical per batch -> softmax exactly
// uniform -> attention output == V, independent of x and Wq. Full op:
//   y[b,:] = (context[b] @ Wv) @ Wo + bo ;  out[b,c,h,w] = y[b,c].
//
// R1 lesson: single-block-per-batch projection was latency-bound (80 µs,
// 0.35% occupancy). This version split-Ks both matmuls for parallelism.

#define BB     4
#define DIMC   512
#define CTXC   768
#define NPIX   2304                      // 48*48
#define PERROW (NPIX / 4)                // 576 float4 per (b,c) row
#define NVEC   (BB * DIMC * PERROW)      // total float4 stores
#define CSPLIT 12                        // 768 / 64
#define KSPLIT 8                         // 512 / 64

// K1: vpart[b][j][d] = sum_{c in chunk j} ctx[b,c] * Wv[c,d]
// 48 blocks x 512 threads; fully unrolled 64-iter loop -> 64 loads in flight.
__global__ __launch_bounds__(DIMC) void ca_vpart_kernel(
    const float* __restrict__ ctx,    // [BB, CTXC]
    const float* __restrict__ Wv,     // [CTXC, DIMC]
    float* __restrict__ vpart)        // [BB, CSPLIT, DIMC]
{
    const int b = blockIdx.x / CSPLIT;
    const int j = blockIdx.x % CSPLIT;
    const int d = threadIdx.x;
    const float* cb = ctx + b * CTXC + j * 64;     // wave-uniform scalars
    const float* wp = Wv + (j * 64) * DIMC + d;    // coalesced columns

    float acc = 0.f;
#pragma unroll
    for (int c = 0; c < 64; ++c)
        acc += cb[c] * wp[c * DIMC];
    vpart[(b * CSPLIT + j) * DIMC + d] = acc;
}

// K2: ypart[b][k][d] = sum_{c in chunk k} v[b,c] * Wo[c,d]
// where v[b,c] is folded from the 12 vparts by the first 64 threads into LDS.
__global__ __launch_bounds__(DIMC) void ca_ypart_kernel(
    const float* __restrict__ vpart,  // [BB, CSPLIT, DIMC]
    const float* __restrict__ Wo,     // [DIMC, DIMC]
    float* __restrict__ ypart)        // [BB, KSPLIT, DIMC]
{
    __shared__ float v_s[64];
    const int b = blockIdx.x / KSPLIT;
    const int k = blockIdx.x % KSPLIT;
    const int d = threadIdx.x;

    if (d < 64) {
        const int c = k * 64 + d;
        float s = 0.f;
#pragma unroll
        for (int j = 0; j < CSPLIT; ++j)
            s += vpart[(b * CSPLIT + j) * DIMC + c];
        v_s[d] = s;
    }
    __syncthreads();

    const float* wp = Wo + (k * 64) * DIMC + d;    // coalesced columns
    float acc = 0.f;
#pragma unroll
    for (int c = 0; c < 64; ++c)
        acc += v_s[c] * wp[c * DIMC];              // LDS broadcast reads
    ypart[(b * KSPLIT + k) * DIMC + d] = acc;
}

// K3: finalize y[b,c] = bo[c] + sum_k ypart[b][k][c] (all L2-resident, 64 KB)
// and broadcast across the 2304 spatial positions with float4 stores.
__global__ __launch_bounds__(256) void ca_bcast_kernel(
    const float* __restrict__ ypart,  // [BB, KSPLIT, DIMC]
    const float* __restrict__ bo,     // [DIMC]
    float4* __restrict__ out)         // [BB, DIMC, PERROW]
{
    const int stride = gridDim.x * blockDim.x;
    for (int i = blockIdx.x * blockDim.x + threadIdx.x; i < NVEC; i += stride) {
        const int row = i / PERROW;            // b*DIMC + c
        const int b = row >> 9;
        const int c = row & (DIMC - 1);
        float v = bo[c];
#pragma unroll
        for (int k = 0; k < KSPLIT; ++k)
            v += ypart[(b * KSPLIT + k) * DIMC + c];
        out[i] = make_float4(v, v, v, v);
    }
}

extern "C" void kernel_launch(void* const* d_in, const int* in_sizes, int n_in,
                              void* d_out, int out_size, void* d_ws, size_t ws_size,
                              hipStream_t stream) {
    // setup_inputs order: x, context, Wq, Wk, Wv, Wo, bo
    const float* ctx = (const float*)d_in[1];
    const float* Wv  = (const float*)d_in[4];
    const float* Wo  = (const float*)d_in[5];
    const float* bo  = (const float*)d_in[6];
    float* out = (float*)d_out;

    float* vpart = (float*)d_ws;                       // 4*12*512 = 96 KB
    float* ypart = vpart + BB * CSPLIT * DIMC;         // 4* 8*512 = 64 KB

    ca_vpart_kernel<<<BB * CSPLIT, DIMC, 0, stream>>>(ctx, Wv, vpart);
    ca_ypart_kernel<<<BB * KSPLIT, DIMC, 0, stream>>>(vpart, Wo, ypart);
    ca_bcast_kernel<<<2048, 256, 0, stream>>>(ypart, bo, (float4*)out);
}

// Round 3
// 87.563 us; speedup vs baseline: 1.6384x; 1.0103x over previous
//
#include <hip/hip_runtime.h>

// Structural collapse (verified passing R1/R2): context is broadcast over all
// spatial positions -> all K/V rows identical per batch -> softmax exactly
// uniform -> attention output == V, independent of x and Wq. Full op:
//   y[b,:] = (context[b] @ Wv) @ Wo + bo ;  out[b,c,h,w] = y[b,c].
//
// R2 lesson: ~60 µs of dur_us is harness-fixed (256 MiB ws re-poison + d_in
// restore visible as fillBufferAligned in rocprof). Our addressable slice is
// ~25 µs; this round shortens per-thread serial chains (32-MAC chunks, 4
// accumulators) and makes the broadcast a pure 1-store-per-thread kernel.

#define BB     4
#define DIMC   512
#define CTXC   768
#define NPIX   2304                       // 48*48
#define PERROW (NPIX / 4)                 // 576 float4 per (b,c) row
#define CSPLIT 24                         // 768 / 32
#define CCH    32
#define KSPLIT 16                         // 512 / 32
#define KCH    32

// K1: vpart[b][j][d] = sum_{c in 32-chunk j} ctx[b,c] * Wv[c,d]
// 96 blocks x 512 threads; fully unrolled, 4 independent accumulators.
__global__ __launch_bounds__(DIMC) void ca_vpart_kernel(
    const float* __restrict__ ctx,    // [BB, CTXC]
    const float* __restrict__ Wv,     // [CTXC, DIMC]
    float* __restrict__ vpart)        // [BB, CSPLIT, DIMC]
{
    const int b = blockIdx.x / CSPLIT;
    const int j = blockIdx.x % CSPLIT;
    const int d = threadIdx.x;
    const float* cb = ctx + b * CTXC + j * CCH;    // wave-uniform scalars
    const float* wp = Wv + (j * CCH) * DIMC + d;   // coalesced columns

    float a0 = 0.f, a1 = 0.f, a2 = 0.f, a3 = 0.f;
#pragma unroll
    for (int c = 0; c < CCH; c += 4) {
        a0 += cb[c + 0] * wp[(c + 0) * DIMC];
        a1 += cb[c + 1] * wp[(c + 1) * DIMC];
        a2 += cb[c + 2] * wp[(c + 2) * DIMC];
        a3 += cb[c + 3] * wp[(c + 3) * DIMC];
    }
    vpart[(b * CSPLIT + j) * DIMC + d] = (a0 + a1) + (a2 + a3);
}

// K2: ypart[b][k][d] = sum_{c in 32-chunk k} v[b,c] * Wo[c,d]
// v folded from the 24 vparts by the first 32 threads into LDS.
__global__ __launch_bounds__(DIMC) void ca_ypart_kernel(
    const float* __restrict__ vpart,  // [BB, CSPLIT, DIMC]
    const float* __restrict__ Wo,     // [DIMC, DIMC]
    float* __restrict__ ypart)        // [BB, KSPLIT, DIMC]
{
    __shared__ float v_s[KCH];
    const int b = blockIdx.x / KSPLIT;
    const int k = blockIdx.x % KSPLIT;
    const int d = threadIdx.x;

    if (d < KCH) {
        const int c = k * KCH + d;
        float s = 0.f;
#pragma unroll
        for (int j = 0; j < CSPLIT; ++j)
            s += vpart[(b * CSPLIT + j) * DIMC + c];   // L2-resident, unrolled
        v_s[d] = s;
    }
    __syncthreads();

    const float* wp = Wo + (k * KCH) * DIMC + d;   // coalesced columns
    float a0 = 0.f, a1 = 0.f, a2 = 0.f, a3 = 0.f;
#pragma unroll
    for (int c = 0; c < KCH; c += 4) {
        a0 += v_s[c + 0] * wp[(c + 0) * DIMC];
        a1 += v_s[c + 1] * wp[(c + 1) * DIMC];
        a2 += v_s[c + 2] * wp[(c + 2) * DIMC];
        a3 += v_s[c + 3] * wp[(c + 3) * DIMC];
    }
    ypart[(b * KSPLIT + k) * DIMC + d] = (a0 + a1) + (a2 + a3);
}

// K3: one block per (b,c) row. Fold y = bo + sum_k ypart (17 wave-uniform L2
// loads, amortized over 576 lanes), then exactly one float4 store per thread.
__global__ __launch_bounds__(576) void ca_bcast_kernel(
    const float* __restrict__ ypart,  // [BB, KSPLIT, DIMC]
    const float* __restrict__ bo,     // [DIMC]
    float4* __restrict__ out)         // [BB*DIMC, PERROW]
{
    const int row = blockIdx.x;            // b*DIMC + c
    const int b = row >> 9;
    const int c = row & (DIMC - 1);
    float v = bo[c];
#pragma unroll
    for (int k = 0; k < KSPLIT; ++k)
        v += ypart[(b * KSPLIT + k) * DIMC + c];
    out[(size_t)row * PERROW + threadIdx.x] = make_float4(v, v, v, v);
}

extern "C" void kernel_launch(void* const* d_in, const int* in_sizes, int n_in,
                              void* d_out, int out_size, void* d_ws, size_t ws_size,
                              hipStream_t stream) {
    // setup_inputs order: x, context, Wq, Wk, Wv, Wo, bo
    const float* ctx = (const float*)d_in[1];
    const float* Wv  = (const float*)d_in[4];
    const float* Wo  = (const float*)d_in[5];
    const float* bo  = (const float*)d_in[6];
    float* out = (float*)d_out;

    float* vpart = (float*)d_ws;                       // 4*24*512 floats
    float* ypart = vpart + BB * CSPLIT * DIMC;         // 4*16*512 floats

    ca_vpart_kernel<<<BB * CSPLIT, DIMC, 0, stream>>>(ctx, Wv, vpart);
    ca_ypart_kernel<<<BB * KSPLIT, DIMC, 0, stream>>>(vpart, Wo, ypart);
    ca_bcast_kernel<<<BB * DIMC, 576, 0, stream>>>(ypart, bo, (float4*)out);
}

// Round 6
// 86.941 us; speedup vs baseline: 1.6501x; 1.0072x over previous
//
#include <hip/hip_runtime.h>

// Structural collapse (verified passing R1-R3): context is broadcast over all
// spatial positions -> all K/V rows identical per batch -> softmax exactly
// uniform -> attention output == V, independent of x and Wq. Full op:
//   y[b,:] = (context[b] @ Wv) @ Wo + bo ;  out[b,c,h,w] = y[b,c].
//
// R3 lesson: compute restructuring is flat -> dispatch-overhead regime.
// R4: fuse the two matmul stages into ONE kernel. In y = v@Wo split over
// 32-wide c-chunks, chunk k only needs v[32k..32k+31] -- disjoint across
// chunks -> each block computes its own v slice in-block (no cross-block dep,
// no redundancy). 3 dispatches -> 2.
// (R4/R5 benches were broker acquisition timeouts — resubmitting unchanged.)

#define BB      4
#define DIMC    512
#define CTXC    768
#define NPIX    2304                  // 48*48
#define PERROW  (NPIX / 4)            // 576 float4 per (b,c) row
#define KSPLIT  16                    // 512 / KCH
#define KCH     32                    // v-values (Wo rows) per block
#define STRIPES 16                    // ctx-dim stripes in phase 1
#define SLEN    (CTXC / STRIPES)      // 48 MACs per thread, phase 1

// Kernel A: one block per (batch, k-chunk). Phase 1: compute the chunk's 32
// v-values (32 outputs x 16 stripes across 512 threads, LDS reduce). Phase 2:
// ypart[b,k,d] = sum_{c in chunk} v[c] * Wo[32k+c, d], coalesced over d.
__global__ __launch_bounds__(DIMC) void ca_y_kernel(
    const float* __restrict__ ctx,    // [BB, CTXC]
    const float* __restrict__ Wv,     // [CTXC, DIMC]
    const float* __restrict__ Wo,     // [DIMC, DIMC]
    float* __restrict__ ypart)        // [BB, KSPLIT, DIMC]
{
    __shared__ float part[STRIPES][KCH];
    __shared__ float v_s[KCH];
    const int b = blockIdx.x / KSPLIT;
    const int k = blockIdx.x % KSPLIT;
    const int t = threadIdx.x;

    // Phase 1: v[k*32 + cl] = sum_e ctx[b,e] * Wv[e, k*32+cl]
    {
        const int cl = t & (KCH - 1);         // which of the 32 outputs
        const int sp = t >> 5;                // which 48-long ctx stripe
        const float* cb = ctx + b * CTXC + sp * SLEN;
        const float* wp = Wv + (sp * SLEN) * DIMC + k * KCH + cl;
        float a0 = 0.f, a1 = 0.f, a2 = 0.f, a3 = 0.f;
#pragma unroll
        for (int e = 0; e < SLEN; e += 4) {
            a0 += cb[e + 0] * wp[(e + 0) * DIMC];
            a1 += cb[e + 1] * wp[(e + 1) * DIMC];
            a2 += cb[e + 2] * wp[(e + 2) * DIMC];
            a3 += cb[e + 3] * wp[(e + 3) * DIMC];
        }
        part[sp][cl] = (a0 + a1) + (a2 + a3);
    }
    __syncthreads();
    if (t < KCH) {
        float s = 0.f;
#pragma unroll
        for (int i = 0; i < STRIPES; ++i)
            s += part[i][t];
        v_s[t] = s;
    }
    __syncthreads();

    // Phase 2: coalesced over d = t.
    {
        const float* wo = Wo + (k * KCH) * DIMC + t;
        float a0 = 0.f, a1 = 0.f, a2 = 0.f, a3 = 0.f;
#pragma unroll
        for (int c = 0; c < KCH; c += 4) {
            a0 += v_s[c + 0] * wo[(c + 0) * DIMC];
            a1 += v_s[c + 1] * wo[(c + 1) * DIMC];
            a2 += v_s[c + 2] * wo[(c + 2) * DIMC];
            a3 += v_s[c + 3] * wo[(c + 3) * DIMC];
        }
        ypart[(b * KSPLIT + k) * DIMC + t] = (a0 + a1) + (a2 + a3);
    }
}

// Kernel B: one block per (b,c) row. Fold y = bo + sum_k ypart (17 uniform
// L2-resident loads amortized over 576 lanes), one float4 store per thread.
__global__ __launch_bounds__(576) void ca_bcast_kernel(
    const float* __restrict__ ypart,  // [BB, KSPLIT, DIMC]
    const float* __restrict__ bo,     // [DIMC]
    float4* __restrict__ out)         // [BB*DIMC, PERROW]
{
    const int row = blockIdx.x;            // b*DIMC + c
    const int b = row >> 9;
    const int c = row & (DIMC - 1);
    float v = bo[c];
#pragma unroll
    for (int k = 0; k < KSPLIT; ++k)
        v += ypart[(b * KSPLIT + k) * DIMC + c];
    out[(size_t)row * PERROW + threadIdx.x] = make_float4(v, v, v, v);
}

extern "C" void kernel_launch(void* const* d_in, const int* in_sizes, int n_in,
                              void* d_out, int out_size, void* d_ws, size_t ws_size,
                              hipStream_t stream) {
    // setup_inputs order: x, context, Wq, Wk, Wv, Wo, bo
    const float* ctx = (const float*)d_in[1];
    const float* Wv  = (const float*)d_in[4];
    const float* Wo  = (const float*)d_in[5];
    const float* bo  = (const float*)d_in[6];
    float* out = (float*)d_out;
    float* ypart = (float*)d_ws;                   // 4*16*512 floats = 128 KB

    ca_y_kernel<<<BB * KSPLIT, DIMC, 0, stream>>>(ctx, Wv, Wo, ypart);
    ca_bcast_kernel<<<BB * DIMC, 576, 0, stream>>>(ypart, bo, (float4*)out);
}